// Round 10
// baseline (64.413 us; speedup 1.0000x reference)
//
#include <hip/hip_runtime.h>
#include <hip/hip_bf16.h>
#include <math.h>

#define NN 8
#define CC 256
#define LL 8192
#define KK 3
#define GG 8
#define GCC 32
#define OMD 48  // 2*G*K
#define TILE_L 128
#define TL 32   // k1a positions per block

typedef __attribute__((ext_vector_type(8))) short short8v;   // 8 bf16 (4 VGPR)
typedef __attribute__((ext_vector_type(4))) float floatx4;

__device__ inline ushort f2bf(float f) {
    uint u = __float_as_uint(f);
    u += 0x7fffu + ((u >> 16) & 1u);   // RNE
    return (ushort)(u >> 16);
}

// branch-free GELU (tanh form) via hardware exp: max |err vs exact| ~3e-3
__device__ inline float gelu_fast(float xn) {
    float u = xn * xn;
    float z = xn * (-1.5957691216f - 0.0713548162726f * u);
    return __fdividef(xn, 1.f + __expf(z));
}

// ---- kernel 0: pack om_w [48][256] into MFMA B-fragment order, bf16 ----------
// wB[((ks*3+nt)*64 + lane)*8 + j] = om_w[16*nt + (lane&15)][32*ks + 8*(lane>>4) + j]
__global__ void k_prep_w(const float* __restrict__ om_w, ushort* __restrict__ wB) {
    int idx = blockIdx.x * 256 + threadIdx.x;   // 12288 total
    if (idx < 8 * 3 * 64 * 8) {
        int j  = idx & 7;
        int l  = (idx >> 3) & 63;
        int nt = (idx >> 9) % 3;
        int ks = idx / 1536;
        int o  = 16 * nt + (l & 15);
        int c  = 32 * ks + 8 * (l >> 4) + j;
        wB[idx] = f2bf(om_w[o * CC + c]);
    }
}

// ---------------- kernel 1a: LN + GELU -> xa bf16 [N,L,C] ---------------------
__global__ __launch_bounds__(256, 8) void k_ln_gelu(
    const float* __restrict__ x,
    const float* __restrict__ ln_w, const float* __restrict__ ln_b,
    __hip_bfloat16* __restrict__ xa)
{
    __shared__ float xs[128 * 33];   // 16896 B
    int n  = blockIdx.y;
    int l0 = blockIdx.x * TL;
    int t  = threadIdx.x;
    int p   = t >> 3;        // position 0..31
    int sub = t & 7;         // channel chunk 0..7
    int pp  = p ^ (sub << 2);

    const float* xbase = x + (size_t)n * CC * LL + l0;
    float r[32];

    #pragma unroll
    for (int half = 0; half < 2; ++half) {
        float4 v[4];
        #pragma unroll
        for (int it = 0; it < 4; ++it) {
            int idx = it * 256 + t;
            int cl  = idx >> 3;
            int l4  = idx & 7;
            v[it] = *reinterpret_cast<const float4*>(
                xbase + (size_t)(half * 128 + cl) * LL + l4 * 4);
        }
        if (half) __syncthreads();
        #pragma unroll
        for (int it = 0; it < 4; ++it) {
            int idx = it * 256 + t;
            int cl  = idx >> 3;
            int l4  = idx & 7;
            int sw  = (cl >> 4) << 2;
            int b   = cl * 33;
            xs[b + ((4 * l4 + 0) ^ sw)] = v[it].x;
            xs[b + ((4 * l4 + 1) ^ sw)] = v[it].y;
            xs[b + ((4 * l4 + 2) ^ sw)] = v[it].z;
            xs[b + ((4 * l4 + 3) ^ sw)] = v[it].w;
        }
        __syncthreads();
        #pragma unroll
        for (int j = 0; j < 16; ++j)
            r[half * 16 + j] = xs[(sub * 16 + j) * 33 + pp];
    }

    float sum = 0.f, sq = 0.f;
    #pragma unroll
    for (int j = 0; j < 32; ++j) { sum += r[j]; sq = fmaf(r[j], r[j], sq); }
    #pragma unroll
    for (int m = 1; m <= 4; m <<= 1) {
        sum += __shfl_xor(sum, m);
        sq  += __shfl_xor(sq, m);
    }
    float mean = sum * (1.f / 256.f);
    float rstd = rsqrtf(sq * (1.f / 256.f) - mean * mean + 1e-6f);

    __hip_bfloat16* xarow = xa + ((size_t)n * LL + l0 + p) * CC;
    #pragma unroll
    for (int half = 0; half < 2; ++half) {
        int cb = half * 128 + sub * 16;
        ushort pk[16];
        #pragma unroll
        for (int q = 0; q < 4; ++q) {
            float4 lw = *reinterpret_cast<const float4*>(ln_w + cb + 4 * q);
            float4 lb = *reinterpret_cast<const float4*>(ln_b + cb + 4 * q);
            float lww[4] = {lw.x, lw.y, lw.z, lw.w};
            float lbb[4] = {lb.x, lb.y, lb.z, lb.w};
            #pragma unroll
            for (int i = 0; i < 4; ++i) {
                int j = 4 * q + i;
                float xn = (r[half * 16 + j] - mean) * rstd * lww[i] + lbb[i];
                pk[j] = f2bf(gelu_fast(xn));
            }
        }
        uint4* dst = reinterpret_cast<uint4*>(xarow + cb);
        #pragma unroll
        for (int q = 0; q < 2; ++q) {
            uint4 w4;
            w4.x = (uint)pk[8*q+0] | ((uint)pk[8*q+1] << 16);
            w4.y = (uint)pk[8*q+2] | ((uint)pk[8*q+3] << 16);
            w4.z = (uint)pk[8*q+4] | ((uint)pk[8*q+5] << 16);
            w4.w = (uint)pk[8*q+6] | ((uint)pk[8*q+7] << 16);
            dst[q] = w4;
        }
    }
}

// ---------------- kernel 1b: om = xa @ wB + om_b via MFMA ---------------------
// one wave per 16-position M-tile; K=256 in 8 steps of 32; N=48 as 3 n-tiles.
__global__ __launch_bounds__(256, 4) void k_om_mfma(
    const __hip_bfloat16* __restrict__ xa, const ushort* __restrict__ wB,
    const float* __restrict__ om_b, float* __restrict__ om)
{
    int t    = threadIdx.x;
    int lane = t & 63;
    int w    = blockIdx.x * 4 + (t >> 6);   // mtile id 0..4095
    int col  = lane & 15;                   // A-row / C-col
    int q    = lane >> 4;                   // k-subgroup / C row-quad
    size_t pos0 = (size_t)w * 16;

    const short8v* Abase = reinterpret_cast<const short8v*>(
        reinterpret_cast<const ushort*>(xa) + (pos0 + col) * CC + q * 8);
    const short8v* Bbase = reinterpret_cast<const short8v*>(wB) + lane;

    floatx4 acc[3] = {{0.f,0.f,0.f,0.f},{0.f,0.f,0.f,0.f},{0.f,0.f,0.f,0.f}};
    #pragma unroll
    for (int ks = 0; ks < 8; ++ks) {
        short8v a = Abase[ks * 4];          // +32 channels per step
        #pragma unroll
        for (int nt = 0; nt < 3; ++nt) {
            short8v b = Bbase[(ks * 3 + nt) * 64];
            acc[nt] = __builtin_amdgcn_mfma_f32_16x16x32_bf16(a, b, acc[nt], 0, 0, 0);
        }
    }
    #pragma unroll
    for (int nt = 0; nt < 3; ++nt) {
        float bias = om_b[nt * 16 + col];
        float* dst = om + (pos0 + q * 4) * OMD + nt * 16 + col;
        #pragma unroll
        for (int i = 0; i < 4; ++i)
            dst[(size_t)i * OMD] = acc[nt][i] + bias;
    }
}

// ---------------- kernel 2: deformable gather + mask aggregation --------------
__global__ __launch_bounds__(256) void k_dcn(
    const __hip_bfloat16* __restrict__ xa, const float* __restrict__ om,
    float* __restrict__ out)
{
    int lt = blockIdx.x, g = blockIdx.y, n = blockIdx.z;
    int l0 = lt * TILE_L;

    __shared__ int   i0_s[TILE_L * KK];
    __shared__ int   i1_s[TILE_L * KK];
    __shared__ float w0_s[TILE_L * KK];
    __shared__ float w1_s[TILE_L * KK];
    __shared__ float out_s[GCC][TILE_L + 4];

    int t = threadIdx.x;

    for (int idx = t; idx < TILE_L * KK; idx += 256) {
        int ll = idx / KK, k = idx - KK * (idx / KK);
        int l = l0 + ll;
        const float* omp = om + ((size_t)n * LL + l) * OMD;
        float off  = omp[g * KK + k];
        float mask = omp[GG * KK + g * KK + k];
        float p  = (float)(l - 1 + k) + off;
        float p0 = floorf(p);
        float w1 = p - p0;
        float w0 = 1.f - w1;
        int i0 = (int)p0;
        int i1 = i0 + 1;
        float ws0 = (i0 >= 0 && i0 < LL) ? mask * w0 : 0.f;
        float ws1 = (i1 >= 0 && i1 < LL) ? mask * w1 : 0.f;
        i0_s[idx] = min(max(i0, 0), LL - 1);
        i1_s[idx] = min(max(i1, 0), LL - 1);
        w0_s[idx] = ws0;
        w1_s[idx] = ws1;
    }
    __syncthreads();

    int cq = t & 7;        // channel quad: channels 4cq..4cq+3
    int ps = t >> 3;       // position slot 0..31
    const __hip_bfloat16* xab = xa + (size_t)n * LL * CC + g * GCC + cq * 4;

    #pragma unroll
    for (int it = 0; it < TILE_L / 32; ++it) {
        int ll = it * 32 + ps;
        float acc0 = 0.f, acc1 = 0.f, acc2 = 0.f, acc3 = 0.f;
        #pragma unroll
        for (int k = 0; k < KK; ++k) {
            int idx = ll * KK + k;
            int i0 = i0_s[idx];
            int i1 = i1_s[idx];
            float a0 = w0_s[idx];
            float a1 = w1_s[idx];
            uint2 r0 = *reinterpret_cast<const uint2*>(xab + (size_t)i0 * CC);
            uint2 r1 = *reinterpret_cast<const uint2*>(xab + (size_t)i1 * CC);
            float v00 = __uint_as_float(r0.x << 16);
            float v01 = __uint_as_float(r0.x & 0xffff0000u);
            float v02 = __uint_as_float(r0.y << 16);
            float v03 = __uint_as_float(r0.y & 0xffff0000u);
            float v10 = __uint_as_float(r1.x << 16);
            float v11 = __uint_as_float(r1.x & 0xffff0000u);
            float v12 = __uint_as_float(r1.y << 16);
            float v13 = __uint_as_float(r1.y & 0xffff0000u);
            acc0 = fmaf(a0, v00, fmaf(a1, v10, acc0));
            acc1 = fmaf(a0, v01, fmaf(a1, v11, acc1));
            acc2 = fmaf(a0, v02, fmaf(a1, v12, acc2));
            acc3 = fmaf(a0, v03, fmaf(a1, v13, acc3));
        }
        out_s[cq * 4 + 0][ll] = acc0;
        out_s[cq * 4 + 1][ll] = acc1;
        out_s[cq * 4 + 2][ll] = acc2;
        out_s[cq * 4 + 3][ll] = acc3;
    }
    __syncthreads();

    // float4 output write: 4 rows per thread, 32 float4 columns
    int c4 = t & 31;       // float4 column
    int r  = t >> 5;       // row 0..7, step 8
    float* op = out + ((size_t)n * CC + (size_t)g * GCC) * LL + l0;
    #pragma unroll
    for (int rr = 0; rr < 4; ++rr) {
        int row = r + rr * 8;
        float4 v = *reinterpret_cast<const float4*>(&out_s[row][c4 * 4]);
        *reinterpret_cast<float4*>(op + (size_t)row * LL + c4 * 4) = v;
    }
}

extern "C" void kernel_launch(void* const* d_in, const int* in_sizes, int n_in,
                              void* d_out, int out_size, void* d_ws, size_t ws_size,
                              hipStream_t stream) {
    const float* x    = (const float*)d_in[0];
    const float* ln_w = (const float*)d_in[1];
    const float* ln_b = (const float*)d_in[2];
    const float* om_w = (const float*)d_in[3];
    const float* om_b = (const float*)d_in[4];
    float* out = (float*)d_out;

    ushort* wB = (ushort*)d_ws;                                  // 24576 B
    __hip_bfloat16* xa = (__hip_bfloat16*)((char*)d_ws + 49152); // 32 MB
    float* om = (float*)((char*)d_ws + 49152 + (size_t)NN * LL * CC * 2); // 12 MB

    k_prep_w<<<48, 256, 0, stream>>>(om_w, wB);

    dim3 g1a(LL / TL, NN);
    k_ln_gelu<<<g1a, 256, 0, stream>>>(x, ln_w, ln_b, xa);

    k_om_mfma<<<1024, 256, 0, stream>>>(xa, wB, om_b, om);

    dim3 grid2(LL / TILE_L, GG, NN);
    k_dcn<<<grid2, 256, 0, stream>>>(xa, om, out);
}

// Round 12
// 58.085 us; speedup vs baseline: 1.1090x; 1.1090x over previous
//
#include <hip/hip_runtime.h>
#include <hip/hip_bf16.h>
#include <math.h>

#define NN 8
#define CC 256
#define LL 8192
#define KK 3
#define GG 8
#define GCC 32
#define OMD 48  // 2*G*K
#define TILE_L 128
#define TL 32   // k1 positions per block

typedef __attribute__((ext_vector_type(8))) short short8v;   // 8 bf16 (4 VGPR)
typedef __attribute__((ext_vector_type(4))) float floatx4;

__device__ inline ushort f2bf(float f) {
    uint u = __float_as_uint(f);
    u += 0x7fffu + ((u >> 16) & 1u);   // RNE
    return (ushort)(u >> 16);
}

// branch-free GELU (tanh form) via hardware exp: max |err vs exact| ~3e-3
__device__ inline float gelu_fast(float xn) {
    float u = xn * xn;
    float z = xn * (-1.5957691216f - 0.0713548162726f * u);
    return __fdividef(xn, 1.f + __expf(z));
}

// ---------------- kernel 1a: LN + GELU -> xa bf16 [N,L,C] ---------------------
// block (0,0) additionally packs om_w into MFMA B-fragment order (wB), used by
// the LATER k_om_mfma kernel (cross-kernel visibility is guaranteed).
__global__ __launch_bounds__(256, 8) void k_ln_gelu(
    const float* __restrict__ x,
    const float* __restrict__ ln_w, const float* __restrict__ ln_b,
    const float* __restrict__ om_w, ushort* __restrict__ wB,
    __hip_bfloat16* __restrict__ xa)
{
    __shared__ float xs[128 * 33];   // 16896 B
    int n  = blockIdx.y;
    int l0 = blockIdx.x * TL;
    int t  = threadIdx.x;
    int p   = t >> 3;        // position 0..31
    int sub = t & 7;         // channel chunk 0..7
    int pp  = p ^ (sub << 2);

    const float* xbase = x + (size_t)n * CC * LL + l0;
    float r[32];

    #pragma unroll
    for (int half = 0; half < 2; ++half) {
        float4 v[4];
        #pragma unroll
        for (int it = 0; it < 4; ++it) {
            int idx = it * 256 + t;
            int cl  = idx >> 3;
            int l4  = idx & 7;
            v[it] = *reinterpret_cast<const float4*>(
                xbase + (size_t)(half * 128 + cl) * LL + l4 * 4);
        }
        if (half) __syncthreads();
        #pragma unroll
        for (int it = 0; it < 4; ++it) {
            int idx = it * 256 + t;
            int cl  = idx >> 3;
            int l4  = idx & 7;
            int sw  = (cl >> 4) << 2;
            int b   = cl * 33;
            xs[b + ((4 * l4 + 0) ^ sw)] = v[it].x;
            xs[b + ((4 * l4 + 1) ^ sw)] = v[it].y;
            xs[b + ((4 * l4 + 2) ^ sw)] = v[it].z;
            xs[b + ((4 * l4 + 3) ^ sw)] = v[it].w;
        }
        __syncthreads();
        #pragma unroll
        for (int j = 0; j < 16; ++j)
            r[half * 16 + j] = xs[(sub * 16 + j) * 33 + pp];
    }

    float sum = 0.f, sq = 0.f;
    #pragma unroll
    for (int j = 0; j < 32; ++j) { sum += r[j]; sq = fmaf(r[j], r[j], sq); }
    #pragma unroll
    for (int m = 1; m <= 4; m <<= 1) {
        sum += __shfl_xor(sum, m);
        sq  += __shfl_xor(sq, m);
    }
    float mean = sum * (1.f / 256.f);
    float rstd = rsqrtf(sq * (1.f / 256.f) - mean * mean + 1e-6f);

    __hip_bfloat16* xarow = xa + ((size_t)n * LL + l0 + p) * CC;
    #pragma unroll
    for (int half = 0; half < 2; ++half) {
        int cb = half * 128 + sub * 16;
        ushort pk[16];
        #pragma unroll
        for (int q = 0; q < 4; ++q) {
            float4 lw = *reinterpret_cast<const float4*>(ln_w + cb + 4 * q);
            float4 lb = *reinterpret_cast<const float4*>(ln_b + cb + 4 * q);
            float lww[4] = {lw.x, lw.y, lw.z, lw.w};
            float lbb[4] = {lb.x, lb.y, lb.z, lb.w};
            #pragma unroll
            for (int i = 0; i < 4; ++i) {
                int j = 4 * q + i;
                float xn = (r[half * 16 + j] - mean) * rstd * lww[i] + lbb[i];
                pk[j] = f2bf(gelu_fast(xn));
            }
        }
        uint4* dst = reinterpret_cast<uint4*>(xarow + cb);
        #pragma unroll
        for (int q = 0; q < 2; ++q) {
            uint4 w4;
            w4.x = (uint)pk[8*q+0] | ((uint)pk[8*q+1] << 16);
            w4.y = (uint)pk[8*q+2] | ((uint)pk[8*q+3] << 16);
            w4.z = (uint)pk[8*q+4] | ((uint)pk[8*q+5] << 16);
            w4.w = (uint)pk[8*q+6] | ((uint)pk[8*q+7] << 16);
            dst[q] = w4;
        }
    }

    // ---- prep tail (block (0,0) only): pack om_w -> wB, bf16 B-fragments ----
    // wB[((ks*3+nt)*64 + lane)*8 + j] = om_w[16*nt + (lane&15)][32*ks + 8*(lane>>4) + j]
    if (blockIdx.x == 0 && blockIdx.y == 0) {
        for (int idx = t; idx < 8 * 3 * 64 * 8; idx += 256) {
            int j  = idx & 7;
            int l  = (idx >> 3) & 63;
            int nt = (idx >> 9) % 3;
            int ks = idx / 1536;
            int o  = 16 * nt + (l & 15);
            int c  = 32 * ks + 8 * (l >> 4) + j;
            wB[idx] = f2bf(om_w[o * CC + c]);
        }
    }
}

// ---------------- kernel 1b: om = xa @ wB + om_b via MFMA ---------------------
// one wave per PAIR of 16-position M-tiles; K=256 in 8 steps; N=48 as 3 ntiles.
// B-loads amortize over 2 MFMAs; 16 independent A-loads in flight per wave.
__global__ __launch_bounds__(256, 4) void k_om_mfma(
    const __hip_bfloat16* __restrict__ xa, const ushort* __restrict__ wB,
    const float* __restrict__ om_b, float* __restrict__ om)
{
    int t    = threadIdx.x;
    int lane = t & 63;
    int col  = lane & 15;                   // A-row / C-col
    int q    = lane >> 4;                   // k-subgroup / C row-quad
    size_t pos0 = ((size_t)blockIdx.x * 8 + (t >> 6) * 2) * 16;  // first mtile

    const ushort* xp = reinterpret_cast<const ushort*>(xa);
    const short8v* A0 = reinterpret_cast<const short8v*>(xp + (pos0 + col) * CC + q * 8);
    const short8v* A1 = reinterpret_cast<const short8v*>(xp + (pos0 + 16 + col) * CC + q * 8);
    const short8v* Bb = reinterpret_cast<const short8v*>(wB) + lane;

    floatx4 c00 = {0.f,0.f,0.f,0.f}, c01 = {0.f,0.f,0.f,0.f}, c02 = {0.f,0.f,0.f,0.f};
    floatx4 c10 = {0.f,0.f,0.f,0.f}, c11 = {0.f,0.f,0.f,0.f}, c12 = {0.f,0.f,0.f,0.f};
    #pragma unroll
    for (int ks = 0; ks < 8; ++ks) {
        short8v a0 = A0[ks * 4];            // +32 channels per step
        short8v a1 = A1[ks * 4];
        short8v b0 = Bb[(ks * 3 + 0) * 64];
        short8v b1 = Bb[(ks * 3 + 1) * 64];
        short8v b2 = Bb[(ks * 3 + 2) * 64];
        c00 = __builtin_amdgcn_mfma_f32_16x16x32_bf16(a0, b0, c00, 0, 0, 0);
        c10 = __builtin_amdgcn_mfma_f32_16x16x32_bf16(a1, b0, c10, 0, 0, 0);
        c01 = __builtin_amdgcn_mfma_f32_16x16x32_bf16(a0, b1, c01, 0, 0, 0);
        c11 = __builtin_amdgcn_mfma_f32_16x16x32_bf16(a1, b1, c11, 0, 0, 0);
        c02 = __builtin_amdgcn_mfma_f32_16x16x32_bf16(a0, b2, c02, 0, 0, 0);
        c12 = __builtin_amdgcn_mfma_f32_16x16x32_bf16(a1, b2, c12, 0, 0, 0);
    }
    float b0 = om_b[col];
    float b1 = om_b[16 + col];
    float b2 = om_b[32 + col];
    {
        float* d = om + (pos0 + q * 4) * OMD + col;
        #pragma unroll
        for (int i = 0; i < 4; ++i) {
            d[(size_t)i * OMD]      = c00[i] + b0;
            d[(size_t)i * OMD + 16] = c01[i] + b1;
            d[(size_t)i * OMD + 32] = c02[i] + b2;
        }
    }
    {
        float* d = om + (pos0 + 16 + q * 4) * OMD + col;
        #pragma unroll
        for (int i = 0; i < 4; ++i) {
            d[(size_t)i * OMD]      = c10[i] + b0;
            d[(size_t)i * OMD + 16] = c11[i] + b1;
            d[(size_t)i * OMD + 32] = c12[i] + b2;
        }
    }
}

// ---------------- kernel 2: deformable gather + mask aggregation --------------
// thread owns 8 consecutive channels (uint4 = 16B gathers)
__global__ __launch_bounds__(256) void k_dcn(
    const __hip_bfloat16* __restrict__ xa, const float* __restrict__ om,
    float* __restrict__ out)
{
    int lt = blockIdx.x, g = blockIdx.y, n = blockIdx.z;
    int l0 = lt * TILE_L;

    __shared__ int   i0_s[TILE_L * KK];
    __shared__ int   i1_s[TILE_L * KK];
    __shared__ float w0_s[TILE_L * KK];
    __shared__ float w1_s[TILE_L * KK];
    __shared__ float out_s[GCC][TILE_L + 4];

    int t = threadIdx.x;

    for (int idx = t; idx < TILE_L * KK; idx += 256) {
        int ll = idx / KK, k = idx - KK * (idx / KK);
        int l = l0 + ll;
        const float* omp = om + ((size_t)n * LL + l) * OMD;
        float off  = omp[g * KK + k];
        float mask = omp[GG * KK + g * KK + k];
        float p  = (float)(l - 1 + k) + off;
        float p0 = floorf(p);
        float w1 = p - p0;
        float w0 = 1.f - w1;
        int i0 = (int)p0;
        int i1 = i0 + 1;
        float ws0 = (i0 >= 0 && i0 < LL) ? mask * w0 : 0.f;
        float ws1 = (i1 >= 0 && i1 < LL) ? mask * w1 : 0.f;
        i0_s[idx] = min(max(i0, 0), LL - 1);
        i1_s[idx] = min(max(i1, 0), LL - 1);
        w0_s[idx] = ws0;
        w1_s[idx] = ws1;
    }
    __syncthreads();

    int cq = t & 3;        // channel oct: channels 8cq..8cq+7
    int ps = t >> 2;       // position slot 0..63
    const __hip_bfloat16* xab = xa + (size_t)n * LL * CC + g * GCC + cq * 8;

    #pragma unroll
    for (int it = 0; it < 2; ++it) {
        int ll = it * 64 + ps;
        float acc[8] = {0.f,0.f,0.f,0.f,0.f,0.f,0.f,0.f};
        #pragma unroll
        for (int k = 0; k < KK; ++k) {
            int idx = ll * KK + k;
            int i0 = i0_s[idx];
            int i1 = i1_s[idx];
            float a0 = w0_s[idx];
            float a1 = w1_s[idx];
            uint4 r0 = *reinterpret_cast<const uint4*>(xab + (size_t)i0 * CC);
            uint4 r1 = *reinterpret_cast<const uint4*>(xab + (size_t)i1 * CC);
            uint u0[4] = {r0.x, r0.y, r0.z, r0.w};
            uint u1[4] = {r1.x, r1.y, r1.z, r1.w};
            #pragma unroll
            for (int d = 0; d < 4; ++d) {
                acc[2*d]   = fmaf(a0, __uint_as_float(u0[d] << 16),
                             fmaf(a1, __uint_as_float(u1[d] << 16), acc[2*d]));
                acc[2*d+1] = fmaf(a0, __uint_as_float(u0[d] & 0xffff0000u),
                             fmaf(a1, __uint_as_float(u1[d] & 0xffff0000u), acc[2*d+1]));
            }
        }
        #pragma unroll
        for (int j = 0; j < 8; ++j) out_s[cq * 8 + j][ll] = acc[j];
    }
    __syncthreads();

    // float4 output write: 4 rows per thread, 32 float4 columns
    int c4 = t & 31;       // float4 column
    int rw = t >> 5;       // row 0..7, step 8
    float* op = out + ((size_t)n * CC + (size_t)g * GCC) * LL + l0;
    #pragma unroll
    for (int rr = 0; rr < 4; ++rr) {
        int row = rw + rr * 8;
        float4 v = *reinterpret_cast<const float4*>(&out_s[row][c4 * 4]);
        *reinterpret_cast<float4*>(op + (size_t)row * LL + c4 * 4) = v;
    }
}

extern "C" void kernel_launch(void* const* d_in, const int* in_sizes, int n_in,
                              void* d_out, int out_size, void* d_ws, size_t ws_size,
                              hipStream_t stream) {
    const float* x    = (const float*)d_in[0];
    const float* ln_w = (const float*)d_in[1];
    const float* ln_b = (const float*)d_in[2];
    const float* om_w = (const float*)d_in[3];
    const float* om_b = (const float*)d_in[4];
    float* out = (float*)d_out;

    ushort* wB = (ushort*)d_ws;                                  // 24576 B
    __hip_bfloat16* xa = (__hip_bfloat16*)((char*)d_ws + 49152); // 32 MB
    float* om = (float*)((char*)d_ws + 49152 + (size_t)NN * LL * CC * 2); // 12 MB

    dim3 g1a(LL / TL, NN);
    k_ln_gelu<<<g1a, 256, 0, stream>>>(x, ln_w, ln_b, om_w, wB, xa);

    k_om_mfma<<<512, 256, 0, stream>>>(xa, wB, om_b, om);

    dim3 grid2(LL / TILE_L, GG, NN);
    k_dcn<<<grid2, 256, 0, stream>>>(xa, om, out);
}